// Round 4
// baseline (367.286 us; speedup 1.0000x reference)
//
#include <hip/hip_runtime.h>
#include <hip/hip_bf16.h>

#define B_   16
#define DF_  1536
#define D_   1024
#define V_   6890
#define PD_  256
#define HID_ 512
#define C_   133
#define CPAD 144    // 9 * 16

typedef short short8 __attribute__((ext_vector_type(8)));
typedef float float4_ __attribute__((ext_vector_type(4)));
typedef unsigned short ushort_t;

#define MFMA16 __builtin_amdgcn_mfma_f32_16x16x32_bf16

__device__ __forceinline__ float b2f(ushort_t u) {
  union { unsigned int i; float f; } x;
  x.i = ((unsigned int)u) << 16;
  return x.f;
}
__device__ __forceinline__ ushort_t f2b(float f) {
  union { float f; unsigned int i; } x;
  x.f = f;
  unsigned int r = (x.i + 0x7fffu + ((x.i >> 16) & 1u)) >> 16;
  return (ushort_t)r;
}
__device__ __forceinline__ unsigned int f22u(float h0, float h1) {
  __hip_bfloat162 hb = __float22bfloat162_rn(make_float2(h0, h1));
  unsigned int u;
  __builtin_memcpy(&u, &hb, sizeof(u));
  return u;
}

// ---------------- prep: WT (padded W_ft2^T), WbT (W_ft1 bottom^T), and
// bias-init of all f64 atomic-accumulate targets. 372384 elems -> 1455 blocks.
__global__ __launch_bounds__(256) void k_prep2(
    const float* __restrict__ Wft2, const float* __restrict__ Wft1,
    const float* __restrict__ bcon, const float* __restrict__ bft1,
    const float* __restrict__ bcls, ushort_t* __restrict__ WT,
    ushort_t* __restrict__ WbT, double* __restrict__ part,
    double* __restrict__ vv, double* __restrict__ att,
    double* __restrict__ attpjd, double* __restrict__ sbuf) {
  int i = blockIdx.x * 256 + threadIdx.x;
  if (i < CPAD * HID_) {
    int c = i >> 9, k = i & (HID_ - 1);
    WT[i] = (c < C_) ? f2b(Wft2[(size_t)k * C_ + c]) : (ushort_t)0;
    return;
  }
  i -= CPAD * HID_;
  if (i < HID_ * PD_) {
    int k = i & (HID_ - 1), pd = i >> 9;
    WbT[(size_t)k * PD_ + pd] = f2b(Wft1[(size_t)(D_ + pd) * HID_ + k]);
    return;
  }
  i -= HID_ * PD_;
  if (i < B_ * D_) { part[i] = (double)bcon[i & (D_ - 1)]; return; }
  i -= B_ * D_;
  if (i < B_ * D_) { vv[i] = 0.0; return; }
  i -= B_ * D_;
  if (i < B_ * D_) { att[i] = 0.0; return; }
  i -= B_ * D_;
  if (i < B_ * HID_) { attpjd[i] = (double)bft1[i & (HID_ - 1)]; return; }
  i -= B_ * HID_;
  if (i < B_ * V_) { sbuf[i] = (double)bcls[i % V_]; return; }
}

// ---------------- batched GEMV body: out[16][N] += A[16][K] @ W[K][N], f64.
// W read once, coalesced 256B/wave. Block = (64 j-lanes x 4 k-subs of 8 k);
// each lane carries 16 batch accumulators. LDS reduce, one f64 atomicAdd
// per (b,j) into the bias-initialized out buffer. smem: 4KB A + 32KB red.
__device__ __forceinline__ void gA_body(const float* __restrict__ A32,
                                        const double* __restrict__ A64,
                                        const float* __restrict__ W,
                                        double* __restrict__ out,
                                        int K, int N, int bx, int by,
                                        char* smem) {
  double* sA = (double*)smem;            // 16 x 32
  double* red = (double*)(smem + 4096);  // 4 x 16 x 64
  int kc0 = by * 32;
  int tid = threadIdx.x;
  for (int i = tid; i < 512; i += 256) {
    int b = i >> 5, kl = i & 31;
    sA[i] = A32 ? (double)A32[(size_t)b * K + kc0 + kl]
                : A64[(size_t)b * K + kc0 + kl];
  }
  __syncthreads();
  int jl = tid & 63, ksub = tid >> 6;
  const float* Wp = W + (size_t)(kc0 + ksub * 8) * N + bx * 64 + jl;
  double acc[16];
#pragma unroll
  for (int b = 0; b < 16; ++b) acc[b] = 0.0;
#pragma unroll
  for (int kk = 0; kk < 8; ++kk) {
    double w = (double)Wp[(size_t)kk * N];
    const double* ap = sA + ksub * 8 + kk;
#pragma unroll
    for (int b = 0; b < 16; ++b) acc[b] += ap[b * 32] * w;  // LDS broadcast
  }
#pragma unroll
  for (int b = 0; b < 16; ++b) red[(ksub * 16 + b) * 64 + jl] = acc[b];
  __syncthreads();
  for (int i = tid; i < 1024; i += 256) {
    int b = i >> 6, jj = i & 63;
    double v = red[(0 * 16 + b) * 64 + jj] + red[(1 * 16 + b) * 64 + jj] +
               red[(2 * 16 + b) * 64 + jj] + red[(3 * 16 + b) * 64 + jj];
    atomicAdd(&out[(size_t)b * N + bx * 64 + jj], v);
  }
}

__global__ __launch_bounds__(256, 4) void k_gA(const float* __restrict__ A32,
                                               const double* __restrict__ A64,
                                               const float* __restrict__ W,
                                               double* __restrict__ out,
                                               int K, int N) {
  __shared__ __align__(16) char smem[36864];
  gA_body(A32, A64, W, out, K, N, blockIdx.x, blockIdx.y, smem);
}

// ---------------- pproj body: PP[64 v][64 n] tile = bf16(pos) @ WbT^T.
// pos tile staged f32->bf16 XOR-swizzled LDS once, A-frags hoisted to regs,
// B-frags from WbT (256KB, L2-resident). smem: 32KB.
__device__ __forceinline__ void pproj_body(const float* __restrict__ pos,
                                           const ushort_t* __restrict__ WbT,
                                           ushort_t* __restrict__ PP,
                                           int bx, int by, char* smem) {
  ushort_t* pb_lds = (ushort_t*)smem;  // 64 rows x 512 B, swizzled
  int wave = threadIdx.x >> 6, lane = threadIdx.x & 63;
  int q = lane >> 4, l15 = lane & 15;
  int vblk = bx * 64;

  for (int i = threadIdx.x; i < 64 * 128; i += 256) {
    int v = i >> 7, e2 = i & 127;
    int vc = vblk + v; vc = vc < V_ ? vc : V_ - 1;
    const float* sp = pos + (size_t)vc * PD_ + e2 * 2;
    unsigned int u = f22u(sp[0], sp[1]);
    int bsw = (e2 * 4) ^ ((v & 7) << 4);
    *(unsigned int*)((char*)pb_lds + v * 512 + bsw) = u;
  }
  __syncthreads();

  int row = wave * 16 + l15;
  short8 afr[8];
#pragma unroll
  for (int kt = 0; kt < 8; ++kt) {
    int jb = kt * 32 + q * 8;
    int bsw = (jb * 2) ^ ((row & 7) << 4);
    afr[kt] = *(const short8*)((const char*)pb_lds + row * 512 + bsw);
  }

  int n0 = by * 64;
  float4_ acc[4] = {};
#pragma unroll 2
  for (int kt = 0; kt < 8; ++kt) {
    int jb = kt * 32 + q * 8;
#pragma unroll
    for (int nf = 0; nf < 4; ++nf) {
      int n = n0 + nf * 16 + l15;
      short8 bfr = *(const short8*)(WbT + (size_t)n * PD_ + jb);
      acc[nf] = MFMA16(afr[kt], bfr, acc[nf], 0, 0, 0);
    }
  }
  int v0w = vblk + wave * 16 + q * 4;
#pragma unroll
  for (int nf = 0; nf < 4; ++nf)
#pragma unroll
    for (int r = 0; r < 4; ++r)
      PP[(size_t)(v0w + r) * HID_ + (n0 + nf * 16 + l15)] = f2b(acc[nf][r]);
}

// ---------------- L2 merged launch: gA(features@W_contact -> part) [768
// blocks] || pproj [864 blocks]. Roles independent; consumers in later
// launches. Flat grid 1632.
__global__ __launch_bounds__(256, 4) void k_stage2(
    const float* __restrict__ features, const float* __restrict__ W_contact,
    double* __restrict__ part, const float* __restrict__ pos,
    const ushort_t* __restrict__ WbT, ushort_t* __restrict__ PP) {
  __shared__ __align__(16) char smem[36864];
  int bid = blockIdx.x;
  if (bid < 768) {
    gA_body(features, nullptr, W_contact, part, DF_, D_, bid & 15, bid >> 4,
            smem);
  } else {
    int b2 = bid - 768;
    pproj_body(pos, WbT, PP, b2 % 108, b2 / 108, smem);
  }
}

// ---------------- cont2 body: sbuf[b][v] += att[b][:] . W_cls[:][v], f64.
// 54 x 16 tiles; 64 v-lanes (float2 -> 128 v) x 4 b-groups. smem: 8KB.
__device__ __forceinline__ void cont2_body(const double* __restrict__ att,
                                           const float* __restrict__ Wcls,
                                           double* __restrict__ sbuf,
                                           int bx, int by, char* smem) {
  double* sa = (double*)smem;  // [16][64]
  int tid = threadIdx.x;
  int k0 = by * 64;
  for (int i = tid; i < 1024; i += 256)
    sa[i] = att[(size_t)(i >> 6) * D_ + k0 + (i & 63)];
  __syncthreads();
  int lane = tid & 63, bg = tid >> 6;
  int v0 = bx * 128 + lane * 2;
  bool ok0 = v0 < V_, ok1 = v0 + 1 < V_;
  int v0c = ok1 ? v0 : 0;
  double acc[4][2] = {};
  const float* wp = Wcls + (size_t)k0 * V_ + v0c;
  const double* ab = sa + bg * 4 * 64;
#pragma unroll 8
  for (int kk = 0; kk < 64; ++kk) {
    float2 w = *(const float2*)(wp + (size_t)kk * V_);
    double w0 = (double)w.x, w1 = (double)w.y;
#pragma unroll
    for (int b = 0; b < 4; ++b) {
      double a = ab[b * 64 + kk];
      acc[b][0] += a * w0;
      acc[b][1] += a * w1;
    }
  }
  if (ok0)
#pragma unroll
    for (int b = 0; b < 4; ++b)
      atomicAdd(&sbuf[(size_t)(bg * 4 + b) * V_ + v0], acc[b][0]);
  if (ok1)
#pragma unroll
    for (int b = 0; b < 4; ++b)
      atomicAdd(&sbuf[(size_t)(bg * 4 + b) * V_ + v0 + 1], acc[b][1]);
}

// ---------------- L5 merged launch: gA(att@W_ft1 -> attpjd) [256 blocks] ||
// cont2(att@W_cls -> sbuf) [864 blocks]. Independent outputs. Flat 1120.
__global__ __launch_bounds__(256, 4) void k_fin5(
    const double* __restrict__ att, const float* __restrict__ Wft1,
    double* __restrict__ attpjd, const float* __restrict__ Wcls,
    double* __restrict__ sbuf) {
  __shared__ __align__(16) char smem[36864];
  int bid = blockIdx.x;
  if (bid < 256) {
    gA_body(nullptr, att, Wft1, attpjd, D_, HID_, bid & 7, bid >> 3, smem);
  } else {
    int b2 = bid - 256;
    cont2_body(att, Wcls, sbuf, b2 % 54, b2 / 54, smem);
  }
}

// ---------------- main (round-1 verified v2 structure):
// preds^T[b] = W_ft2^T @ relu(attproj[b] + PP^T), + sigmoid/mask from sbuf.
// grid (108, 8): v-tile 64 (wave owns 16 v), batch pair, BK=64 (8 iters),
// double-buffered WT slices with write-side XOR swizzle. 3 blocks/CU.
__global__ __launch_bounds__(256, 3) void k_main(
    const ushort_t* __restrict__ WT, const ushort_t* __restrict__ PP,
    const double* __restrict__ attpjd, const double* __restrict__ sbuf,
    const float* __restrict__ bft2, float* __restrict__ out0,
    float* __restrict__ out1) {
  __shared__ ushort_t swt[2][CPAD * 64];  // 2 x 18432 B, rows 128B swizzled
  __shared__ float attp[2][HID_];         // 4 KB
  int b0 = blockIdx.y * 2;
  int wave = threadIdx.x >> 6, lane = threadIdx.x & 63;
  int q = lane >> 4, l15 = lane & 15;
  int vbase = blockIdx.x * 64 + wave * 16;

  for (int i = threadIdx.x; i < 2 * HID_; i += 256)
    attp[i >> 9][i & (HID_ - 1)] =
        (float)attpjd[(size_t)(b0 + (i >> 9)) * HID_ + (i & (HID_ - 1))];

  // stage WT slice kt (144 rows x 64 k): byte' = byte ^ ((row&7)<<4).
  auto stage = [&](int kt, int buf) {
#pragma unroll
    for (int ii = 0; ii < 5; ++ii) {
      int i = ii * 256 + threadIdx.x;
      if (i < 1152) {
        int row = i >> 3, seg = i & 7;
        short8 w = *(const short8*)(WT + (size_t)row * HID_ + kt * 64 + seg * 8);
        int bsw = (seg * 16) ^ ((row & 7) << 4);
        *(short8*)((char*)swt[buf] + row * 128 + bsw) = w;
      }
    }
  };

  const ushort_t* pbase = PP + (size_t)(vbase + l15) * HID_;
  short8 pcur[2], pnext[2];
  pcur[0] = *(const short8*)(pbase + q * 8);
  pcur[1] = *(const short8*)(pbase + 32 + q * 8);
  stage(0, 0);
  __syncthreads();

  float4_ acc[2][9] = {};  // [batch][c-tile]
  for (int kt = 0; kt < 8; ++kt) {
    int buf = kt & 1;
    if (kt < 7) stage(kt + 1, buf ^ 1);
    pnext[0] = pcur[0]; pnext[1] = pcur[1];
    if (kt < 7) {
      pnext[0] = *(const short8*)(pbase + (kt + 1) * 64 + q * 8);
      pnext[1] = *(const short8*)(pbase + (kt + 1) * 64 + 32 + q * 8);
    }
    short8 bfr[2][2];  // [batch][ksub]
#pragma unroll
    for (int ss = 0; ss < 2; ++ss) {
      int kb = kt * 64 + ss * 32 + q * 8;
      float pf[8];
#pragma unroll
      for (int jj = 0; jj < 8; ++jj) pf[jj] = b2f((ushort_t)pcur[ss][jj]);
#pragma unroll
      for (int bb = 0; bb < 2; ++bb) {
        float4_ a0 = *(const float4_*)&attp[bb][kb];
        float4_ a1 = *(const float4_*)&attp[bb][kb + 4];
        float af[8];
#pragma unroll
        for (int e = 0; e < 4; ++e) { af[e] = a0[e]; af[4 + e] = a1[e]; }
        unsigned int uu[4];
#pragma unroll
        for (int jj = 0; jj < 8; jj += 2) {
          float h0 = af[jj] + pf[jj];
          float h1 = af[jj + 1] + pf[jj + 1];
          h0 = h0 > 0.f ? h0 : 0.f;
          h1 = h1 > 0.f ? h1 : 0.f;
          uu[jj >> 1] = f22u(h0, h1);
        }
        __builtin_memcpy(&bfr[bb][ss], uu, 16);
      }
    }
#pragma unroll
    for (int ss = 0; ss < 2; ++ss) {
      int cb = ss * 64 + q * 16;
#pragma unroll
      for (int mt = 0; mt < 9; ++mt) {
        int row = mt * 16 + l15;
        short8 a = *(const short8*)((const char*)swt[buf] + row * 128 +
                                    (cb ^ ((row & 7) << 4)));
        acc[0][mt] = MFMA16(a, bfr[0][ss], acc[0][mt], 0, 0, 0);
        acc[1][mt] = MFMA16(a, bfr[1][ss], acc[1][mt], 0, 0, 0);
      }
    }
    pcur[0] = pnext[0]; pcur[1] = pnext[1];
    __syncthreads();
  }

  int n = vbase + l15;
  int ncl = n < V_ ? n : V_ - 1;
  bool mk[2];
#pragma unroll
  for (int bb = 0; bb < 2; ++bb) {
    double sv = sbuf[(size_t)(b0 + bb) * V_ + ncl];
    mk[bb] = (n < V_) && (sv > 0.0);
    if (q == 0 && n < V_)
      out0[(size_t)(b0 + bb) * V_ + n] = (float)(1.0 / (1.0 + exp(-sv)));
  }
#pragma unroll
  for (int bb = 0; bb < 2; ++bb) {
    float* ob = out1 + (size_t)(b0 + bb) * C_ * V_;
#pragma unroll
    for (int mt = 0; mt < 9; ++mt)
#pragma unroll
      for (int r = 0; r < 4; ++r) {
        int c = mt * 16 + q * 4 + r;
        if (c < C_ && n < V_) {
          float val = mk[bb] ? acc[bb][mt][r] + bft2[c] : 0.f;
          ob[(size_t)c * V_ + n] = val;
        }
      }
  }
}

extern "C" void kernel_launch(void* const* d_in, const int* in_sizes, int n_in,
                              void* d_out, int out_size, void* d_ws, size_t ws_size,
                              hipStream_t stream) {
  const float* features  = (const float*)d_in[0];
  // W_scene/b_scene/Wq/Wk are mathematically dead: softmax over a length-1
  // sequence is identically 1, so att = (part @ Wv) @ Wo.
  const float* W_contact = (const float*)d_in[3];
  const float* b_contact = (const float*)d_in[4];
  const float* Wv        = (const float*)d_in[7];
  const float* Wo        = (const float*)d_in[8];
  const float* W_cls     = (const float*)d_in[9];
  const float* b_cls     = (const float*)d_in[10];
  const float* pos_emb   = (const float*)d_in[11];
  const float* W_ft1     = (const float*)d_in[12];
  const float* b_ft1     = (const float*)d_in[13];
  const float* W_ft2     = (const float*)d_in[14];
  const float* b_ft2     = (const float*)d_in[15];

  char* ws = (char*)d_ws;
  double*   part   = (double*)(ws);                  // 131072 B
  double*   vv     = (double*)(ws + 131072);         // 131072 B
  double*   att    = (double*)(ws + 262144);         // 131072 B
  double*   attpjd = (double*)(ws + 393216);         // 65536 B
  double*   sbuf   = (double*)(ws + 458752);         // 881920 B (pad 882688)
  ushort_t* wt     = (ushort_t*)(ws + 1341440);      // 147456 B
  ushort_t* wbt    = (ushort_t*)(ws + 1488896);      // 262144 B
  ushort_t* pp     = (ushort_t*)(ws + 1751040);      // 7077888 B -> ~8.8 MB

  float* out0 = (float*)d_out;
  float* out1 = out0 + (size_t)B_ * V_;

  // L1: transposes + bias inits
  k_prep2<<<1455, 256, 0, stream>>>(W_ft2, W_ft1, b_contact, b_ft1, b_cls,
                                    wt, wbt, part, vv, att, attpjd, sbuf);
  // L2: part = features@W_contact  ||  PP = pos@WbT^T
  k_stage2<<<1632, 256, 0, stream>>>(features, W_contact, part, pos_emb, wbt, pp);
  // L3, L4: serial D->D gemvs
  k_gA<<<dim3(16, 32), 256, 0, stream>>>(nullptr, part, Wv, vv, D_, D_);
  k_gA<<<dim3(16, 32), 256, 0, stream>>>(nullptr, vv, Wo, att, D_, D_);
  // L5: attpjd = att@W_ft1  ||  sbuf = att@W_cls
  k_fin5<<<1120, 256, 0, stream>>>(att, W_ft1, attpjd, W_cls, sbuf);
  // L6: epilogue GEMM + mask/sigmoid
  k_main<<<dim3(108, 8), 256, 0, stream>>>(wt, pp, attpjd, sbuf, b_ft2, out0, out1);
}

// Round 5
// 246.014 us; speedup vs baseline: 1.4929x; 1.4929x over previous
//
#include <hip/hip_runtime.h>
#include <hip/hip_bf16.h>

#define B_   16
#define DF_  1536
#define D_   1024
#define V_   6890
#define PD_  256
#define HID_ 512
#define C_   133
#define CPAD 144    // 9 * 16

typedef short short8 __attribute__((ext_vector_type(8)));
typedef float float4_ __attribute__((ext_vector_type(4)));
typedef unsigned short ushort_t;

#define MFMA16 __builtin_amdgcn_mfma_f32_16x16x32_bf16

__device__ __forceinline__ float b2f(ushort_t u) {
  union { unsigned int i; float f; } x;
  x.i = ((unsigned int)u) << 16;
  return x.f;
}
__device__ __forceinline__ ushort_t f2b(float f) {
  union { float f; unsigned int i; } x;
  x.f = f;
  unsigned int r = (x.i + 0x7fffu + ((x.i >> 16) & 1u)) >> 16;
  return (ushort_t)r;
}
__device__ __forceinline__ unsigned int f22u(float h0, float h1) {
  __hip_bfloat162 hb = __float22bfloat162_rn(make_float2(h0, h1));
  unsigned int u;
  __builtin_memcpy(&u, &hb, sizeof(u));
  return u;
}

// ---------------- prep: WT (padded W_ft2^T), WbT (W_ft1 bottom^T), and
// bias-init of all f64 atomic-accumulate targets. 372384 elems -> 1455 blocks.
__global__ __launch_bounds__(256) void k_prep2(
    const float* __restrict__ Wft2, const float* __restrict__ Wft1,
    const float* __restrict__ bcon, const float* __restrict__ bft1,
    const float* __restrict__ bcls, ushort_t* __restrict__ WT,
    ushort_t* __restrict__ WbT, double* __restrict__ part,
    double* __restrict__ vv, double* __restrict__ att,
    double* __restrict__ attpjd, double* __restrict__ sbuf) {
  int i = blockIdx.x * 256 + threadIdx.x;
  if (i < CPAD * HID_) {
    int c = i >> 9, k = i & (HID_ - 1);
    WT[i] = (c < C_) ? f2b(Wft2[(size_t)k * C_ + c]) : (ushort_t)0;
    return;
  }
  i -= CPAD * HID_;
  if (i < HID_ * PD_) {
    int k = i & (HID_ - 1), pd = i >> 9;
    WbT[(size_t)k * PD_ + pd] = f2b(Wft1[(size_t)(D_ + pd) * HID_ + k]);
    return;
  }
  i -= HID_ * PD_;
  if (i < B_ * D_) { part[i] = (double)bcon[i & (D_ - 1)]; return; }
  i -= B_ * D_;
  if (i < B_ * D_) { vv[i] = 0.0; return; }
  i -= B_ * D_;
  if (i < B_ * D_) { att[i] = 0.0; return; }
  i -= B_ * D_;
  if (i < B_ * HID_) { attpjd[i] = (double)bft1[i & (HID_ - 1)]; return; }
  i -= B_ * HID_;
  if (i < B_ * V_) { sbuf[i] = (double)bcls[i % V_]; return; }
}

// ---------------- batched GEMV: out[16][N] += A[16][K] @ W[K][N], f64.
// W read ONCE total, coalesced. Grid (N/64, K/32): 512-768 blocks (2-3/CU)
// so latency is hidden by TLP. 256 thr = 64 j-lanes x 4 k-subs (8 k each);
// each lane carries all 16 batch accumulators (one W load -> 16 FMAs).
// LDS reduce over k-subs, then one f64 atomicAdd per (b,j) into the
// bias-initialized out buffer. (R3-proven ~10us per GEMV.)
__global__ __launch_bounds__(256) void k_gA(const float* __restrict__ A32,
                                            const double* __restrict__ A64,
                                            const float* __restrict__ W,
                                            double* __restrict__ out,
                                            int K, int N) {
  __shared__ double sA[16 * 32];        // 4 KB
  __shared__ double red[4 * 16 * 64];   // 32 KB
  int kc0 = blockIdx.y * 32;
  int tid = threadIdx.x;
  for (int i = tid; i < 512; i += 256) {
    int b = i >> 5, kl = i & 31;
    sA[i] = A32 ? (double)A32[(size_t)b * K + kc0 + kl]
                : A64[(size_t)b * K + kc0 + kl];
  }
  __syncthreads();
  int jl = tid & 63, ksub = tid >> 6;
  int j = blockIdx.x * 64 + jl;
  const float* Wp = W + (size_t)(kc0 + ksub * 8) * N + j;
  double acc[16];
#pragma unroll
  for (int b = 0; b < 16; ++b) acc[b] = 0.0;
#pragma unroll
  for (int kk = 0; kk < 8; ++kk) {
    double w = (double)Wp[(size_t)kk * N];
    const double* ap = sA + ksub * 8 + kk;
#pragma unroll
    for (int b = 0; b < 16; ++b) acc[b] += ap[b * 32] * w;  // LDS broadcast
  }
#pragma unroll
  for (int b = 0; b < 16; ++b) red[(ksub * 16 + b) * 64 + jl] = acc[b];
  __syncthreads();
  for (int i = tid; i < 1024; i += 256) {
    int b = i >> 6, jj = i & 63;
    double v = red[(0 * 16 + b) * 64 + jj] + red[(1 * 16 + b) * 64 + jj] +
               red[(2 * 16 + b) * 64 + jj] + red[(3 * 16 + b) * 64 + jj];
    atomicAdd(&out[(size_t)b * N + blockIdx.x * 64 + jj], v);
  }
}

// ---------------- s[b][v] += att[b][:] . W_cls[:][v], f64.
// Grid (54, 16) = 864 blocks (3.4/CU). 256 thr = 64 v-lanes (float2 -> 128 v
// per block) x 4 b-groups of 4 batches. W_cls read once, coalesced.
__global__ __launch_bounds__(256) void k_cont2(const double* __restrict__ att,
                                               const float* __restrict__ Wcls,
                                               double* __restrict__ sbuf) {
  __shared__ double sa[16 * 64];  // 8 KB: att chunk [16][64]
  int tid = threadIdx.x;
  int k0 = blockIdx.y * 64;
  for (int i = tid; i < 1024; i += 256)
    sa[i] = att[(size_t)(i >> 6) * D_ + k0 + (i & 63)];
  __syncthreads();
  int lane = tid & 63, bg = tid >> 6;
  int v0 = blockIdx.x * 128 + lane * 2;
  bool ok0 = v0 < V_, ok1 = v0 + 1 < V_;
  int v0c = ok1 ? v0 : 0;  // float2 fully in-bounds for every k row
  double acc[4][2] = {};
  const float* wp = Wcls + (size_t)k0 * V_ + v0c;
  const double* ab = sa + bg * 4 * 64;
#pragma unroll 8
  for (int kk = 0; kk < 64; ++kk) {
    float2 w = *(const float2*)(wp + (size_t)kk * V_);
    double w0 = (double)w.x, w1 = (double)w.y;
#pragma unroll
    for (int b = 0; b < 4; ++b) {
      double a = ab[b * 64 + kk];  // LDS broadcast
      acc[b][0] += a * w0;
      acc[b][1] += a * w1;
    }
  }
  if (ok0)
#pragma unroll
    for (int b = 0; b < 4; ++b)
      atomicAdd(&sbuf[(size_t)(bg * 4 + b) * V_ + v0], acc[b][0]);
  if (ok1)
#pragma unroll
    for (int b = 0; b < 4; ++b)
      atomicAdd(&sbuf[(size_t)(bg * 4 + b) * V_ + v0 + 1], acc[b][1]);
}

// ---------------- PP[v][k_out] = bf16(pos) @ WbT^T via MFMA.
// P0-proven structure: NO LDS staging. A-frags loaded directly from pos
// (2 x 16B per kt) and converted in-register (same RNE values -> PP
// bit-identical); B-frags from L2-resident WbT. Grid (108,8) = 864 blocks,
// zero LDS -> high occupancy, deep load pipelining.
__global__ __launch_bounds__(256) void k_pproj(const float* __restrict__ pos,
                                               const ushort_t* __restrict__ WbT,
                                               ushort_t* __restrict__ PP) {
  int wave = threadIdx.x >> 6, lane = threadIdx.x & 63;
  int q = lane >> 4, l15 = lane & 15;
  int m0 = blockIdx.x * 64 + wave * 16;        // v tile
  int n0 = blockIdx.y * 64;                    // k_out tile
  int vc = m0 + l15; vc = vc < V_ ? vc : V_ - 1;
  const float* pr = pos + (size_t)vc * PD_;
  float4_ acc[4] = {};
#pragma unroll 2
  for (int kt = 0; kt < 8; ++kt) {
    int jb = kt * 32 + q * 8;
    float4_ a0 = *(const float4_*)(pr + jb);
    float4_ a1 = *(const float4_*)(pr + jb + 4);
    unsigned int uu[4];
    uu[0] = f22u(a0[0], a0[1]);
    uu[1] = f22u(a0[2], a0[3]);
    uu[2] = f22u(a1[0], a1[1]);
    uu[3] = f22u(a1[2], a1[3]);
    short8 afr;
    __builtin_memcpy(&afr, uu, 16);
#pragma unroll
    for (int nf = 0; nf < 4; ++nf) {
      int n = n0 + nf * 16 + l15;
      short8 bfr = *(const short8*)(WbT + (size_t)n * PD_ + jb);
      acc[nf] = MFMA16(afr, bfr, acc[nf], 0, 0, 0);
    }
  }
  int v0w = m0 + q * 4;
#pragma unroll
  for (int nf = 0; nf < 4; ++nf)
#pragma unroll
    for (int r = 0; r < 4; ++r)
      PP[(size_t)(v0w + r) * HID_ + (n0 + nf * 16 + l15)] = f2b(acc[nf][r]);
}

// ---------------- main (R0-measured 47us structure):
// preds^T[b] = W_ft2^T @ relu(attproj[b] + PP^T), plus sigmoid/mask from sbuf.
// grid (54, 8): v-tile 128, batch pair. WT k-slice double-buffered in LDS.
__global__ __launch_bounds__(256, 2) void k_main(const ushort_t* __restrict__ WT,
                                                 const ushort_t* __restrict__ PP,
                                                 const double* __restrict__ attpjd,
                                                 const double* __restrict__ sbuf,
                                                 const float* __restrict__ bft2,
                                                 float* __restrict__ out0,
                                                 float* __restrict__ out1) {
  __shared__ ushort_t swt[2][CPAD * 32];   // 2 x 9216 B
  __shared__ float attp[2][HID_];          // 4 KB
  int b0 = blockIdx.y * 2;
  int wave = threadIdx.x >> 6, lane = threadIdx.x & 63;
  int q = lane >> 4, l15 = lane & 15;
  int vbase = blockIdx.x * 128 + wave * 32;

  for (int i = threadIdx.x; i < 2 * HID_; i += 256)
    attp[i >> 9][i & (HID_ - 1)] =
        (float)attpjd[(size_t)(b0 + (i >> 9)) * HID_ + (i & (HID_ - 1))];

  auto stage = [&](int kt, int buf) {
#pragma unroll
    for (int ii = 0; ii < 3; ++ii) {
      int i = ii * 256 + threadIdx.x;
      if (i < 576) {
        int row = i >> 2, seg = i & 3;
        *(short8*)&swt[buf][row * 32 + seg * 8] =
            *(const short8*)(WT + (size_t)row * HID_ + kt * 32 + seg * 8);
      }
    }
  };
  stage(0, 0);

  const ushort_t* pbase0 = PP + (size_t)(vbase + l15) * HID_;
  const ushort_t* pbase1 = PP + (size_t)(vbase + 16 + l15) * HID_;
  short8 pcur[2];
  pcur[0] = *(const short8*)(pbase0 + q * 8);
  pcur[1] = *(const short8*)(pbase1 + q * 8);
  __syncthreads();

  float4_ acc[2][9][2] = {};
  for (int kt = 0; kt < 16; ++kt) {
    int buf = kt & 1;
    int kb = kt * 32 + q * 8;
    if (kt < 15) stage(kt + 1, buf ^ 1);
    short8 pnext[2] = {pcur[0], pcur[1]};
    if (kt < 15) {
      pnext[0] = *(const short8*)(pbase0 + kb + 32);
      pnext[1] = *(const short8*)(pbase1 + kb + 32);
    }
    float pf[2][8];
#pragma unroll
    for (int nf = 0; nf < 2; ++nf)
#pragma unroll
      for (int jj = 0; jj < 8; ++jj)
        pf[nf][jj] = b2f((ushort_t)pcur[nf][jj]);
    float af[2][8];
#pragma unroll
    for (int bb = 0; bb < 2; ++bb) {
      float4_ a0 = *(const float4_*)&attp[bb][kb];
      float4_ a1 = *(const float4_*)&attp[bb][kb + 4];
#pragma unroll
      for (int e = 0; e < 4; ++e) { af[bb][e] = a0[e]; af[bb][4 + e] = a1[e]; }
    }
    short8 bfr[2][2];
#pragma unroll
    for (int bb = 0; bb < 2; ++bb)
#pragma unroll
      for (int nf = 0; nf < 2; ++nf) {
        unsigned int uu[4];
#pragma unroll
        for (int jj = 0; jj < 8; jj += 2) {
          float h0 = af[bb][jj]     + pf[nf][jj];
          float h1 = af[bb][jj + 1] + pf[nf][jj + 1];
          h0 = h0 > 0.f ? h0 : 0.f;
          h1 = h1 > 0.f ? h1 : 0.f;
          uu[jj >> 1] = f22u(h0, h1);
        }
        __builtin_memcpy(&bfr[bb][nf], uu, 16);
      }
#pragma unroll
    for (int mt = 0; mt < 9; ++mt) {
      short8 a = *(const short8*)&swt[buf][(mt * 16 + l15) * 32 + q * 8];
      acc[0][mt][0] = MFMA16(a, bfr[0][0], acc[0][mt][0], 0, 0, 0);
      acc[0][mt][1] = MFMA16(a, bfr[0][1], acc[0][mt][1], 0, 0, 0);
      acc[1][mt][0] = MFMA16(a, bfr[1][0], acc[1][mt][0], 0, 0, 0);
      acc[1][mt][1] = MFMA16(a, bfr[1][1], acc[1][mt][1], 0, 0, 0);
    }
    pcur[0] = pnext[0];
    pcur[1] = pnext[1];
    __syncthreads();
  }

  bool mk[2][2];
  int  nn[2];
#pragma unroll
  for (int nf = 0; nf < 2; ++nf) {
    int n = vbase + nf * 16 + l15;
    nn[nf] = n;
    int ncl = n < V_ ? n : V_ - 1;
#pragma unroll
    for (int bb = 0; bb < 2; ++bb) {
      double sv = sbuf[(size_t)(b0 + bb) * V_ + ncl];
      mk[bb][nf] = (n < V_) && (sv > 0.0);
      if (q == 0 && n < V_)
        out0[(size_t)(b0 + bb) * V_ + n] = (float)(1.0 / (1.0 + exp(-sv)));
    }
  }
#pragma unroll
  for (int bb = 0; bb < 2; ++bb) {
    float* ob = out1 + (size_t)(b0 + bb) * C_ * V_;
#pragma unroll
    for (int mt = 0; mt < 9; ++mt)
#pragma unroll
      for (int r = 0; r < 4; ++r) {
        int c = mt * 16 + q * 4 + r;
        if (c < C_) {
          float bias = bft2[c];
#pragma unroll
          for (int nf = 0; nf < 2; ++nf)
            if (nn[nf] < V_) {
              float val = mk[bb][nf] ? acc[bb][mt][nf][r] + bias : 0.f;
              ob[(size_t)c * V_ + nn[nf]] = val;
            }
        }
      }
  }
}

extern "C" void kernel_launch(void* const* d_in, const int* in_sizes, int n_in,
                              void* d_out, int out_size, void* d_ws, size_t ws_size,
                              hipStream_t stream) {
  const float* features  = (const float*)d_in[0];
  // W_scene/b_scene/Wq/Wk are mathematically dead: softmax over a length-1
  // sequence is identically 1, so att = (part @ Wv) @ Wo.
  const float* W_contact = (const float*)d_in[3];
  const float* b_contact = (const float*)d_in[4];
  const float* Wv        = (const float*)d_in[7];
  const float* Wo        = (const float*)d_in[8];
  const float* W_cls     = (const float*)d_in[9];
  const float* b_cls     = (const float*)d_in[10];
  const float* pos_emb   = (const float*)d_in[11];
  const float* W_ft1     = (const float*)d_in[12];
  const float* b_ft1     = (const float*)d_in[13];
  const float* W_ft2     = (const float*)d_in[14];
  const float* b_ft2     = (const float*)d_in[15];

  char* ws = (char*)d_ws;
  double*   part   = (double*)(ws);                  // 131072 B
  double*   vv     = (double*)(ws + 131072);         // 131072 B
  double*   att    = (double*)(ws + 262144);         // 131072 B
  double*   attpjd = (double*)(ws + 393216);         // 65536 B
  double*   sbuf   = (double*)(ws + 458752);         // 881920 B (pad 882688)
  ushort_t* wt     = (ushort_t*)(ws + 1341440);      // 147456 B
  ushort_t* wbt    = (ushort_t*)(ws + 1488896);      // 262144 B
  ushort_t* pp     = (ushort_t*)(ws + 1751040);      // 7077888 B -> ~8.8 MB

  float* out0 = (float*)d_out;
  float* out1 = out0 + (size_t)B_ * V_;

  k_prep2<<<1455, 256, 0, stream>>>(W_ft2, W_ft1, b_contact, b_ft1, b_cls,
                                    wt, wbt, part, vv, att, attpjd, sbuf);
  k_pproj<<<dim3(108, 8), 256, 0, stream>>>(pos_emb, wbt, pp);
  k_gA<<<dim3(16, 48), 256, 0, stream>>>(features, nullptr, W_contact, part, DF_, D_);
  k_gA<<<dim3(16, 32), 256, 0, stream>>>(nullptr, part, Wv, vv, D_, D_);
  k_gA<<<dim3(16, 32), 256, 0, stream>>>(nullptr, vv, Wo, att, D_, D_);
  k_gA<<<dim3(8, 32), 256, 0, stream>>>(nullptr, att, W_ft1, attpjd, D_, HID_);
  k_cont2<<<dim3(54, 16), 256, 0, stream>>>(att, W_cls, sbuf);
  k_main<<<dim3(54, 8), 256, 0, stream>>>(wt, pp, attpjd, sbuf, b_ft2, out0, out1);
}